// Round 18
// baseline (519.128 us; speedup 1.0000x reference)
//
#include <hip/hip_runtime.h>
#include <hip/hip_bf16.h>
#include <math.h>

#define N_NODES 20000
#define M_PAD   20096          // 157*128; all row-dim ws buffers padded to this
#define N_EDGES 320000
#define N_GRAPHS 64
#define D_IN 771
#define KP   800               // padded K for projection (multiple of 32)
#define HDIM 256
#define L_LAYERS 5

typedef __attribute__((ext_vector_type(8))) short  bf16x8;
typedef __attribute__((ext_vector_type(8))) unsigned short u16x8;
typedef __attribute__((ext_vector_type(4))) float  f32x4;

typedef __attribute__((address_space(3))) void       lds_void;
typedef __attribute__((address_space(1))) const void gconst_void;

__device__ __forceinline__ void gload16(const void* g, void* l) {
    __builtin_amdgcn_global_load_lds((gconst_void*)g, (lds_void*)l, 16, 0, 0);
}

__device__ __forceinline__ unsigned short f2bf(float f) {
    unsigned int u = __float_as_uint(f);
    return (unsigned short)((u + 0x7FFFu + ((u >> 16) & 1u)) >> 16);  // RNE
}
__device__ __forceinline__ float bf2f(unsigned short h) {
    return __uint_as_float(((unsigned int)h) << 16);
}

// swizzle: 16B slot XOR x(r), x(r)=(r>>1)&3  ->  2-way (free) bank aliasing
__device__ __forceinline__ int swz_src_elems(int lane, int lr) {
    return ((((lane & 3) * 16) ^ (((lr >> 1) & 3) << 4)) >> 1);
}
__device__ __forceinline__ int swz_read_bytes(int lane, int r) {
    return (((lane >> 4) * 16) ^ (((r >> 1) & 3) << 4));
}

// ---------------- prep kernels (bf16 casts / transposes, one-time) ----------
// 8 elems/thread (16B store, 32B of reads) — G13 vectorization.
__global__ __launch_bounds__(256)
void prep_x(const float* __restrict__ x, unsigned short* __restrict__ xb) {
    int chunk = blockIdx.x * 256 + threadIdx.x;     // 8-elem chunks
    if (chunk >= N_NODES * (KP / 8)) return;
    int r  = chunk / (KP / 8);
    int k0 = (chunk % (KP / 8)) * 8;
    const float* xr = x + (size_t)r * D_IN;
    u16x8 o;
    #pragma unroll
    for (int i = 0; i < 8; i++) {
        int k = k0 + i;
        o[i] = f2bf(k < D_IN ? xr[k] : 0.f);
    }
    *(u16x8*)(xb + (size_t)r * KP + k0) = o;
}
__global__ void prep_projw(const float* __restrict__ w, unsigned short* __restrict__ wt) {
    int i = blockIdx.x * 256 + threadIdx.x;                // over 256*800, wt[n][k]
    if (i >= HDIM * KP) return;
    int n = i / KP, k = i % KP;
    wt[i] = f2bf(k < D_IN ? w[(size_t)k * HDIM + n] : 0.f);
}
__global__ void prep_cast1(const float* __restrict__ a, unsigned short* __restrict__ ab,
                           int n) {
    int i = blockIdx.x * 256 + threadIdx.x;
    if (i < n) ab[i] = f2bf(a[i]);
}

// W_eff[l][c][j] = sum_t conv_w[l][j][t] * w_ih[c][t]   (fused msg+gi weight)
// fp32 tiled GEMM, bf16 output in [n=c][k=j] layout for gru staging.
__global__ __launch_bounds__(256)
void weff_gemm(const float* __restrict__ wih, const float* __restrict__ convw,
               unsigned short* __restrict__ weff) {
    __shared__ float As[16][68];
    __shared__ float Bs[16][68];
    const int tid = threadIdx.x;
    const int c0 = blockIdx.x * 64, j0 = blockIdx.y * 64;
    const int l  = blockIdx.z;
    const float* Wc = convw + (size_t)l * HDIM * HDIM;
    const int tm = (tid & 15) * 4, tn = (tid >> 4) * 4;
    const int ar = tid >> 2, ac = (tid & 3) * 4;
    float acc[4][4] = {};
    for (int t0 = 0; t0 < HDIM; t0 += 16) {
        float4 av = *(const float4*)(wih + (size_t)(c0 + ar) * HDIM + t0 + ac);
        float4 bv = *(const float4*)(Wc  + (size_t)(j0 + ar) * HDIM + t0 + ac);
        As[ac + 0][ar] = av.x; As[ac + 1][ar] = av.y;
        As[ac + 2][ar] = av.z; As[ac + 3][ar] = av.w;
        Bs[ac + 0][ar] = bv.x; Bs[ac + 1][ar] = bv.y;
        Bs[ac + 2][ar] = bv.z; Bs[ac + 3][ar] = bv.w;
        __syncthreads();
        #pragma unroll
        for (int kk = 0; kk < 16; kk++) {
            float aa[4] = {As[kk][tm], As[kk][tm+1], As[kk][tm+2], As[kk][tm+3]};
            float bb[4] = {Bs[kk][tn], Bs[kk][tn+1], Bs[kk][tn+2], Bs[kk][tn+3]};
            #pragma unroll
            for (int i = 0; i < 4; i++)
                #pragma unroll
                for (int j = 0; j < 4; j++) acc[i][j] += aa[i] * bb[j];
        }
        __syncthreads();
    }
    #pragma unroll
    for (int i = 0; i < 4; i++)
        #pragma unroll
        for (int j = 0; j < 4; j++)
            weff[(size_t)l * 3 * HDIM * HDIM + (size_t)(c0 + tm + i) * HDIM + j0 + tn + j] =
                f2bf(acc[i][j]);
}

// ---------------- generic bf16 MFMA GEMM: C[M,256] = A[M,K] @ Bt[N,K]^T -----
// 128x128 tile, 4 waves (2x2), wave tile 64x64. 2-phase double-buffered LDS.
// (used only for the input projection; bf16-only output)
template<int EPI>   // 0: plain, store Cb; 1: bias+relu, store Cb
__global__ __launch_bounds__(256)
void mm128(const unsigned short* __restrict__ A, int lda,
           const unsigned short* __restrict__ Bt, int ldb,
           const float* __restrict__ bias,
           unsigned short* __restrict__ Cb, int nk) {
    __shared__ char lds[32768];                 // 2 x (8KB A + 8KB B)
    const int tid = threadIdx.x;
    const int lane = tid & 63, wave = tid >> 6;
    const int wm = wave >> 1, wn = wave & 1;
    const int row0 = blockIdx.x * 128, col0 = blockIdx.y * 128;
    const int lr = lane >> 2;
    const int kle = swz_src_elems(lane, lr);

    const unsigned short* sA[2];
    const unsigned short* sB[2];
    #pragma unroll
    for (int j = 0; j < 2; ++j) {
        int c = wave * 2 + j;
        sA[j] = A  + (size_t)(row0 + c * 16 + lr) * lda + kle;
        sB[j] = Bt + (size_t)(col0 + c * 16 + lr) * ldb + kle;
    }

    f32x4 acc[4][4];
    #pragma unroll
    for (int i = 0; i < 4; i++)
        #pragma unroll
        for (int j = 0; j < 4; j++) acc[i][j] = (f32x4){0.f, 0.f, 0.f, 0.f};

    auto stage = [&](int buf, int ks) {
        #pragma unroll
        for (int j = 0; j < 2; ++j) {
            int c = wave * 2 + j;
            gload16(sA[j] + ks * 32, lds + buf * 16384 + c * 1024);
            gload16(sB[j] + ks * 32, lds + buf * 16384 + 8192 + c * 1024);
        }
    };

    stage(0, 0);
    __syncthreads();
    for (int ks = 0; ks < nk; ++ks) {
        const int cur = ks & 1;
        if (ks + 1 < nk) stage(cur ^ 1, ks + 1);
        char* L = lds + cur * 16384;
        bf16x8 af[4], bfr[4];
        #pragma unroll
        for (int f = 0; f < 4; ++f) {
            int r = wm * 64 + f * 16 + (lane & 15);
            af[f] = *(const bf16x8*)(L + r * 64 + swz_read_bytes(lane, r));
            int cb = wn * 64 + f * 16 + (lane & 15);
            bfr[f] = *(const bf16x8*)(L + 8192 + cb * 64 + swz_read_bytes(lane, cb));
        }
        #pragma unroll
        for (int i = 0; i < 4; i++)
            #pragma unroll
            for (int j = 0; j < 4; j++)
                acc[i][j] = __builtin_amdgcn_mfma_f32_16x16x32_bf16(af[i], bfr[j], acc[i][j], 0, 0, 0);
        if (ks + 1 < nk) __syncthreads();
    }
    #pragma unroll
    for (int i = 0; i < 4; i++) {
        #pragma unroll
        for (int j = 0; j < 4; j++) {
            int cc = col0 + wn * 64 + j * 16 + (lane & 15);
            #pragma unroll
            for (int ri = 0; ri < 4; ++ri) {
                int rr = row0 + wm * 64 + i * 16 + (lane >> 4) * 4 + ri;
                float v = acc[i][j][ri];
                if (EPI == 1) { v += bias[cc]; v = fmaxf(v, 0.f); }
                Cb[(size_t)rr * HDIM + cc] = f2bf(v);
            }
        }
    }
}

// ---------------- fused GRU v8: counted-vmcnt pipeline + 2 row-tiles --------
// Two 64-row tiles per block share the staged B slabs: 20KB/step (A0,A1,B r/z/n),
// 10 ds_reads, 24 MFMA per step -> double compute per barrier, B-traffic per
// output halved. 3x20KB LDS ring, depth-2 prefetch, s_waitcnt vmcnt(5) + raw
// barrier (k+2's 5 loads stay in flight). (256,2): 2 blocks/CU, 256 reg/wave
// budget fits 128-reg acc without spill. Grid 628 = 157 row-pairs x 4 cols;
// col = bx&3 => each XCD (bx&7) sees one weight panel (R15 locality for free).
template<int FINAL>
__global__ __launch_bounds__(256, 2)
void gru_mfma(const unsigned short* __restrict__ aggb, const unsigned short* __restrict__ hb,
              const unsigned short* __restrict__ weff, const unsigned short* __restrict__ whh,
              const float* __restrict__ bih, const float* __restrict__ bhh,
              float* __restrict__ hfN, unsigned short* __restrict__ hbN) {
    __shared__ char lds[61440];                   // 3 x 20KB ring
    const int tid = threadIdx.x;
    const int lane = tid & 63, wave = tid >> 6;   // 4 waves
    const int wm = wave >> 1, wn = wave & 1;      // 2 x 2
    const int bx = blockIdx.x;                    // [0, 628)
    const int col0  = (bx & 3) * 64;
    const int rp    = bx >> 2;                    // row pair [0,157)
    const int row0a = rp * 128;
    const int row0b = row0a + 64;
    const int lr = lane >> 2;
    const int laneoff = lr * HDIM + swz_src_elems(lane, lr);  // per-lane elems

    // per-wave staging sources: 5 chunks each (20 total of 1KB).
    // c<4: A0 rows; c<8: A1 rows; c>=8: B slab s=(c-8)>>2, sub (c-8)&3.
    const unsigned short* p0[5];
    const unsigned short* p1[5];
    #pragma unroll
    for (int j = 0; j < 5; ++j) {
        int c = wave * 5 + j;
        const unsigned short *q0, *q1;
        int uo;
        if (c < 4)      { q0 = aggb; q1 = hb; uo = (row0a + c * 16) * HDIM; }
        else if (c < 8) { q0 = aggb; q1 = hb; uo = (row0b + (c - 4) * 16) * HDIM; }
        else {
            int s = (c - 8) >> 2, c4 = (c - 8) & 3;
            q0 = weff; q1 = whh;
            uo = (s * HDIM + col0 + c4 * 16) * HDIM;
        }
        uo = __builtin_amdgcn_readfirstlane(uo);
        p0[j] = q0 + uo + laneoff;
        p1[j] = q1 + uo + laneoff;
    }

    f32x4 accR[2][2][2], accZ[2][2][2], accNI[2][2][2], accNH[2][2][2];
    #pragma unroll
    for (int t = 0; t < 2; t++)
        #pragma unroll
        for (int i = 0; i < 2; i++)
            #pragma unroll
            for (int j = 0; j < 2; j++) {
                accR[t][i][j] = (f32x4){0.f, 0.f, 0.f, 0.f};
                accZ[t][i][j] = (f32x4){0.f, 0.f, 0.f, 0.f};
                accNI[t][i][j] = (f32x4){0.f, 0.f, 0.f, 0.f};
                accNH[t][i][j] = (f32x4){0.f, 0.f, 0.f, 0.f};
            }

    auto stage = [&](int buf, int gks) {
        #pragma unroll
        for (int j = 0; j < 5; ++j) {
            const unsigned short* s = (gks < 8 ? p0[j] : p1[j]) + (gks & 7) * 32;
            gload16(s, lds + buf * 20480 + (wave * 5 + j) * 1024);
        }
    };

    // prologue: depth-2 prefetch; certify buf0 (5 loads), keep buf1 in flight.
    stage(0, 0);
    stage(1, 1);
    asm volatile("s_waitcnt vmcnt(5)" ::: "memory");
    __builtin_amdgcn_s_barrier();

    #pragma unroll
    for (int ks = 0; ks < 16; ++ks) {
        if (ks + 2 < 16) stage((ks + 2) % 3, ks + 2);
        char* L = lds + (ks % 3) * 20480;
        bf16x8 a0[2], a1[2], br[2], bz[2], bn[2];
        #pragma unroll
        for (int f = 0; f < 2; ++f) {
            int r = wm * 32 + f * 16 + (lane & 15);
            int ao = r * 64 + swz_read_bytes(lane, r);
            a0[f] = *(const bf16x8*)(L + ao);
            a1[f] = *(const bf16x8*)(L + 4096 + ao);
            int rb = wn * 32 + f * 16 + (lane & 15);
            int so = rb * 64 + swz_read_bytes(lane, rb);
            br[f] = *(const bf16x8*)(L + 8192 + so);
            bz[f] = *(const bf16x8*)(L + 12288 + so);
            bn[f] = *(const bf16x8*)(L + 16384 + so);
        }
        #pragma unroll
        for (int fr = 0; fr < 2; fr++)
            #pragma unroll
            for (int fc = 0; fc < 2; fc++) {
                accR[0][fr][fc] = __builtin_amdgcn_mfma_f32_16x16x32_bf16(a0[fr], br[fc], accR[0][fr][fc], 0, 0, 0);
                accR[1][fr][fc] = __builtin_amdgcn_mfma_f32_16x16x32_bf16(a1[fr], br[fc], accR[1][fr][fc], 0, 0, 0);
                accZ[0][fr][fc] = __builtin_amdgcn_mfma_f32_16x16x32_bf16(a0[fr], bz[fc], accZ[0][fr][fc], 0, 0, 0);
                accZ[1][fr][fc] = __builtin_amdgcn_mfma_f32_16x16x32_bf16(a1[fr], bz[fc], accZ[1][fr][fc], 0, 0, 0);
                if (ks < 8) {
                    accNI[0][fr][fc] = __builtin_amdgcn_mfma_f32_16x16x32_bf16(a0[fr], bn[fc], accNI[0][fr][fc], 0, 0, 0);
                    accNI[1][fr][fc] = __builtin_amdgcn_mfma_f32_16x16x32_bf16(a1[fr], bn[fc], accNI[1][fr][fc], 0, 0, 0);
                } else {
                    accNH[0][fr][fc] = __builtin_amdgcn_mfma_f32_16x16x32_bf16(a0[fr], bn[fc], accNH[0][fr][fc], 0, 0, 0);
                    accNH[1][fr][fc] = __builtin_amdgcn_mfma_f32_16x16x32_bf16(a1[fr], bn[fc], accNH[1][fr][fc], 0, 0, 0);
                }
            }
        if (ks < 14) {
            asm volatile("s_waitcnt vmcnt(5)" ::: "memory");   // k+1 done, k+2 in flight
            __builtin_amdgcn_s_barrier();
        } else if (ks == 14) {
            asm volatile("s_waitcnt vmcnt(0)" ::: "memory");   // drain last tile
            __builtin_amdgcn_s_barrier();
        }
    }
    #pragma unroll
    for (int t = 0; t < 2; t++) {
        const int row0t = t ? row0b : row0a;
        #pragma unroll
        for (int fr = 0; fr < 2; fr++)
            #pragma unroll
            for (int fc = 0; fc < 2; fc++) {
                int cc = col0 + wn * 32 + fc * 16 + (lane & 15);
                float brz = bih[cc]            + bhh[cc];
                float bzz = bih[HDIM + cc]     + bhh[HDIM + cc];
                float bin = bih[2 * HDIM + cc];
                float bhn = bhh[2 * HDIM + cc];
                #pragma unroll
                for (int ri = 0; ri < 4; ++ri) {
                    int rr = row0t + wm * 32 + fr * 16 + (lane >> 4) * 4 + ri;
                    float xr = accR[t][fr][fc][ri] + brz;
                    float xz = accZ[t][fr][fc][ri] + bzz;
                    float gn = accNI[t][fr][fc][ri] + bin;
                    float hn = accNH[t][fr][fc][ri] + bhn;
                    float r_ = 1.f / (1.f + expf(-xr));
                    float z_ = 1.f / (1.f + expf(-xz));
                    float n_ = tanhf(gn + r_ * hn);
                    float ho = bf2f(hb[(size_t)rr * HDIM + cc]);  // L2-hot
                    float v  = (1.f - z_) * n_ + z_ * ho;
                    if (FINAL) hfN[(size_t)rr * HDIM + cc] = v;
                    hbN[(size_t)rr * HDIM + cc] = f2bf(v);
                }
            }
    }
}

// -------------------------- CSR build ---------------------------------------
__global__ void edge_count(const int* __restrict__ ei, int* __restrict__ deg, int E) {
    int e = blockIdx.x * 256 + threadIdx.x;
    if (e < E) atomicAdd(&deg[ei[E + e]], 1);
}
__global__ __launch_bounds__(1024)
void scan_rowptr(const int* __restrict__ deg, int* __restrict__ rowptr, int N) {
    __shared__ int bs[1024];
    const int tid = threadIdx.x;
    const int CH = (N + 1023) / 1024;
    const int base = tid * CH;
    int sum = 0;
    for (int i = 0; i < CH; i++) { int idx = base + i; sum += (idx < N) ? deg[idx] : 0; }
    bs[tid] = sum; __syncthreads();
    for (int off = 1; off < 1024; off <<= 1) {
        int v = (tid >= off) ? bs[tid - off] : 0;
        __syncthreads();
        bs[tid] += v;
        __syncthreads();
    }
    int run = (tid > 0) ? bs[tid - 1] : 0;
    for (int i = 0; i < CH; i++) {
        int idx = base + i;
        if (idx < N) { rowptr[idx] = run; run += deg[idx]; }
    }
    if (tid == 0) rowptr[N] = bs[1023];
}
__global__ void edge_bucket(const int* __restrict__ ei, int* __restrict__ cursor,
                            int* __restrict__ csrc, int E) {
    int e = blockIdx.x * 256 + threadIdx.x;
    if (e < E) {
        int d = ei[E + e];
        int p = atomicAdd(&cursor[d], 1);
        csrc[p] = ei[e];
    }
}

// agg v3: one wave per node; QUARTER-wave (16 lanes) per edge, 32B/lane,
// 2x unroll -> 8 row-gathers in flight; combine via shfl_xor(16,32).
__global__ __launch_bounds__(256)
void agg_bf16(const unsigned short* __restrict__ m, const int* __restrict__ rowptr,
              const int* __restrict__ csrc, unsigned short* __restrict__ agg, int N) {
    int wv = (blockIdx.x * 256 + threadIdx.x) >> 6;
    int lane = threadIdx.x & 63;
    if (wv >= N) return;
    const int q = lane >> 4, l16 = lane & 15;
    int s0 = rowptr[wv], s1 = rowptr[wv + 1];
    float a[16] = {};
    int e = s0 + q;
    for (; e + 4 < s1; e += 8) {            // 2 edges per quarter in flight
        const unsigned short* rA = m + (size_t)csrc[e] * HDIM + l16 * 16;
        const unsigned short* rB = m + (size_t)csrc[e + 4] * HDIM + l16 * 16;
        u16x8 vA0 = *(const u16x8*)rA, vA1 = *(const u16x8*)(rA + 8);
        u16x8 vB0 = *(const u16x8*)rB, vB1 = *(const u16x8*)(rB + 8);
        #pragma unroll
        for (int i = 0; i < 8; i++) {
            a[i]     += bf2f(vA0[i]) + bf2f(vB0[i]);
            a[8 + i] += bf2f(vA1[i]) + bf2f(vB1[i]);
        }
    }
    for (; e < s1; e += 4) {
        const unsigned short* rA = m + (size_t)csrc[e] * HDIM + l16 * 16;
        u16x8 vA0 = *(const u16x8*)rA, vA1 = *(const u16x8*)(rA + 8);
        #pragma unroll
        for (int i = 0; i < 8; i++) {
            a[i]     += bf2f(vA0[i]);
            a[8 + i] += bf2f(vA1[i]);
        }
    }
    #pragma unroll
    for (int i = 0; i < 16; i++) {
        a[i] += __shfl_xor(a[i], 16);
        a[i] += __shfl_xor(a[i], 32);
    }
    if (q == 0) {
        u16x8 o0, o1;
        #pragma unroll
        for (int i = 0; i < 8; i++) { o0[i] = f2bf(a[i]); o1[i] = f2bf(a[8 + i]); }
        *(u16x8*)(agg + (size_t)wv * HDIM + l16 * 16)     = o0;
        *(u16x8*)(agg + (size_t)wv * HDIM + l16 * 16 + 8) = o1;
    }
}

// -------------------------- attention + head --------------------------------
__global__ void seg_starts(const int* __restrict__ batch, int* __restrict__ starts,
                           int N, int G) {
    int n = blockIdx.x * 256 + threadIdx.x;
    if (n > N) return;
    int b  = (n < N) ? batch[n] : G;
    int bp = (n == 0) ? -1 : batch[n - 1];
    for (int g = bp + 1; g <= b; g++) starts[g] = n;
}

// att scores v2: 32-row tiles (625 blocks, 2x waves/SIMD), float4 LDS reads.
__global__ __launch_bounds__(256)
void att_scores2(const float* __restrict__ h, const float* __restrict__ w1,
                 const float* __restrict__ b1, const float* __restrict__ w2,
                 const float* __restrict__ b2, float* __restrict__ scores) {
    __shared__ float As[16][36];
    __shared__ float Bs[16][132];
    __shared__ float red[32][33];
    const int tid = threadIdx.x;
    const int row0 = blockIdx.x * 32;
    const int tm = (tid & 7) * 4, tn = (tid >> 3) * 4;
    const int ar = tid >> 3, ac = (tid & 7) * 2;    // A stage: 32 rows x 16k, 2/thread
    const int br = tid >> 4, bc = (tid & 15) * 8;   // B stage: 16k x 128, 8/thread
    float acc[4][4] = {};
    for (int k0 = 0; k0 < HDIM; k0 += 16) {
        float2 av = {0.f, 0.f};
        int arow = row0 + ar;
        if (arow < N_NODES) av = *(const float2*)(h + (size_t)arow * HDIM + k0 + ac);
        As[ac][ar] = av.x; As[ac + 1][ar] = av.y;
        *(float4*)&Bs[br][bc]     = *(const float4*)(w1 + (size_t)(k0 + br) * 128 + bc);
        *(float4*)&Bs[br][bc + 4] = *(const float4*)(w1 + (size_t)(k0 + br) * 128 + bc + 4);
        __syncthreads();
        #pragma unroll
        for (int kk = 0; kk < 16; kk++) {
            float4 a4 = *(const float4*)&As[kk][tm];
            float4 b4 = *(const float4*)&Bs[kk][tn];
            float aa[4] = {a4.x, a4.y, a4.z, a4.w};
            float bb[4] = {b4.x, b4.y, b4.z, b4.w};
            #pragma unroll
            for (int i = 0; i < 4; i++)
                #pragma unroll
                for (int j = 0; j < 4; j++) acc[i][j] += aa[i] * bb[j];
        }
        __syncthreads();
    }
    #pragma unroll
    for (int i = 0; i < 4; i++) {
        float s = 0.f;
        #pragma unroll
        for (int j = 0; j < 4; j++)
            s += tanhf(acc[i][j] + b1[tn + j]) * w2[tn + j];
        red[tm + i][tid >> 3] = s;
    }
    __syncthreads();
    if (tid < 32) {
        float s = 0.f;
        #pragma unroll
        for (int g = 0; g < 32; g++) s += red[tid][g];
        int n = row0 + tid;
        if (n < N_NODES) scores[n] = s + b2[0];
    }
}

// per-graph max + denom: one wave per graph
__global__ __launch_bounds__(256)
void seg_stats(const float* __restrict__ scores, const int* __restrict__ starts,
               float* __restrict__ gmax, float* __restrict__ gden) {
    int wv = (blockIdx.x * 256 + threadIdx.x) >> 6;
    int lane = threadIdx.x & 63;
    if (wv >= N_GRAPHS) return;
    int s0 = starts[wv], s1 = starts[wv + 1];
    float mx = -1e30f;
    for (int n = s0 + lane; n < s1; n += 64) mx = fmaxf(mx, scores[n]);
    #pragma unroll
    for (int off = 32; off > 0; off >>= 1) mx = fmaxf(mx, __shfl_xor(mx, off));
    float se = 0.f;
    for (int n = s0 + lane; n < s1; n += 64) se += expf(scores[n] - mx);
    #pragma unroll
    for (int off = 32; off > 0; off >>= 1) se += __shfl_xor(se, off);
    if (lane == 0) { gmax[wv] = mx; gden[wv] = se; }
}

__global__ void node_weights(const float* __restrict__ scores, const int* __restrict__ batch,
                             const float* __restrict__ gmax, const float* __restrict__ gden,
                             float* __restrict__ wn) {
    int n = blockIdx.x * 256 + threadIdx.x;
    if (n >= N_NODES) return;
    int g = batch[n];
    float d = gden[g];
    wn[n] = (d > 0.f) ? expf(scores[n] - gmax[g]) / d : 0.f;
}

// deterministic 4-stripe weighted pool: block (g,s) handles nodes n≡s (mod 4)
__global__ __launch_bounds__(256)
void pool_partial(const float* __restrict__ h, const float* __restrict__ wn,
                  const int* __restrict__ starts, float* __restrict__ part) {
    int g = blockIdx.x, s = blockIdx.y, tid = threadIdx.x;
    int s0 = starts[g], s1 = starts[g + 1];
    float acc = 0.f;
    for (int n = s0 + s; n < s1; n += 4)
        acc += wn[n] * h[(size_t)n * HDIM + tid];
    part[((size_t)(g * 4 + s)) * HDIM + tid] = acc;
}
__global__ __launch_bounds__(256)
void pool_reduce(const float* __restrict__ part, float* __restrict__ pooled) {
    int g = blockIdx.x, tid = threadIdx.x;
    float s = 0.f;
    #pragma unroll
    for (int i = 0; i < 4; i++) s += part[((size_t)(g * 4 + i)) * HDIM + tid];
    pooled[g * HDIM + tid] = s;
}

__global__ __launch_bounds__(128)
void classify(const float* __restrict__ pooled, const float* __restrict__ w1,
              const float* __restrict__ b1, const float* __restrict__ w2,
              const float* __restrict__ b2, float* __restrict__ out) {
    int g = blockIdx.x;
    int tid = threadIdx.x;
    float acc = 0.f;
    for (int k = 0; k < HDIM; k++) acc += pooled[g * HDIM + k] * w1[k * 128 + tid];
    float t = fmaxf(acc + b1[tid], 0.f);
    float v = t * w2[tid];
    __shared__ float red[128];
    red[tid] = v; __syncthreads();
    for (int off = 64; off > 0; off >>= 1) {
        if (tid < off) red[tid] += red[tid + off];
        __syncthreads();
    }
    if (tid == 0) out[g] = red[0] + b2[0];
}

// ---------------------------------------------------------------------------
extern "C" void kernel_launch(void* const* d_in, const int* in_sizes, int n_in,
                              void* d_out, int out_size, void* d_ws, size_t ws_size,
                              hipStream_t stream) {
    const float* x      = (const float*)d_in[0];
    const int*   ei     = (const int*)  d_in[1];
    const int*   batch  = (const int*)  d_in[2];
    const float* proj_w = (const float*)d_in[3];
    const float* proj_b = (const float*)d_in[4];
    const float* conv_w = (const float*)d_in[5];
    const float* w_ih   = (const float*)d_in[6];
    const float* w_hh   = (const float*)d_in[7];
    const float* b_ih   = (const float*)d_in[8];
    const float* b_hh   = (const float*)d_in[9];
    const float* att_w1 = (const float*)d_in[10];
    const float* att_b1 = (const float*)d_in[11];
    const float* att_w2 = (const float*)d_in[12];
    const float* att_b2 = (const float*)d_in[13];
    const float* cls_w1 = (const float*)d_in[14];
    const float* cls_b1 = (const float*)d_in[15];
    const float* cls_w2 = (const float*)d_in[16];
    const float* cls_b2 = (const float*)d_in[17];
    float* out = (float*)d_out;

    char* ws = (char*)d_ws;
    size_t off = 0;
    auto alloc = [&](size_t bytes) -> void* {
        void* p = ws + off;
        off = (off + bytes + 255) & ~(size_t)255;
        return p;
    };
    // persistent
    float*          hfF    = (float*)         alloc((size_t)M_PAD * HDIM * 4);  // final h (attention)
    unsigned short* hb0    = (unsigned short*)alloc((size_t)M_PAD * HDIM * 2);
    unsigned short* hb1    = (unsigned short*)alloc((size_t)M_PAD * HDIM * 2);
    unsigned short* whhb   = (unsigned short*)alloc((size_t)3 * HDIM * HDIM * 2);
    unsigned short* weffb  = (unsigned short*)alloc((size_t)L_LAYERS * 3 * HDIM * HDIM * 2);
    unsigned short* projWT = (unsigned short*)alloc((size_t)HDIM * KP * 2);
    int*   rowptr = (int*)  alloc((N_NODES + 1) * 4);
    int*   cursor = (int*)  alloc((N_NODES + 1) * 4);
    int*   deg    = (int*)  alloc(N_NODES * 4);
    int*   csrc   = (int*)  alloc(N_EDGES * 4);
    float* scores = (float*)alloc(N_NODES * 4);
    int*   starts = (int*)  alloc((N_GRAPHS + 1) * 4);
    float* gmax   = (float*)alloc(N_GRAPHS * 4);
    float* gden   = (float*)alloc(N_GRAPHS * 4);
    float* wnode  = (float*)alloc(N_NODES * 4);
    float* ppart  = (float*)alloc((size_t)N_GRAPHS * 4 * HDIM * 4);
    float* pooled = (float*)alloc((size_t)N_GRAPHS * HDIM * 4);
    // union region: xb (proj phase) overlaps aggb (layer phase)
    char* U = (char*)alloc((size_t)M_PAD * KP * 2);
    unsigned short* xb   = (unsigned short*)U;
    unsigned short* aggb = (unsigned short*)U;
    (void)ws_size; (void)in_sizes; (void)n_in; (void)out_size;

    // ---- one-time prep ----
    prep_x     <<<dim3((N_NODES * (KP / 8) + 255) / 256), dim3(256), 0, stream>>>(x, xb);
    prep_projw <<<dim3((HDIM * KP) / 256), dim3(256), 0, stream>>>(proj_w, projWT);
    prep_cast1 <<<dim3((3 * HDIM * HDIM) / 256), dim3(256), 0, stream>>>(
        w_hh, whhb, 3 * HDIM * HDIM);
    // fused msg+gi weights: W_eff[l] = Wih . Wc[l]^T contraction
    weff_gemm<<<dim3(12, 4, L_LAYERS), dim3(256), 0, stream>>>(w_ih, conv_w, weffb);

    // ---- input projection (+bias+relu) -> hb0 (bf16 only) ----
    mm128<1><<<dim3(M_PAD / 128, 2), dim3(256), 0, stream>>>(
        xb, KP, projWT, KP, proj_b, hb0, KP / 32);

    // ---- CSR by dst ----
    hipMemsetAsync(deg, 0, N_NODES * 4, stream);
    edge_count<<<dim3((N_EDGES + 255) / 256), dim3(256), 0, stream>>>(ei, deg, N_EDGES);
    scan_rowptr<<<dim3(1), dim3(1024), 0, stream>>>(deg, rowptr, N_NODES);
    hipMemcpyAsync(cursor, rowptr, (N_NODES + 1) * 4, hipMemcpyDeviceToDevice, stream);
    edge_bucket<<<dim3((N_EDGES + 255) / 256), dim3(256), 0, stream>>>(ei, cursor, csrc, N_EDGES);
    seg_starts<<<dim3((N_NODES + 256) / 256), dim3(256), 0, stream>>>(batch, starts,
                                                                      N_NODES, N_GRAPHS);

    // ---- 5 message-passing layers (msg GEMM folded into W_eff; bf16 h) ----
    unsigned short* hbc = hb0;  unsigned short* hbn = hb1;
    for (int l = 0; l < L_LAYERS; l++) {
        agg_bf16<<<dim3((N_NODES * 64) / 256), dim3(256), 0, stream>>>(
            hbc, rowptr, csrc, aggb, N_NODES);
        if (l < L_LAYERS - 1)
            gru_mfma<0><<<dim3((M_PAD / 128) * 4), dim3(256), 0, stream>>>(
                aggb, hbc, weffb + (size_t)l * 3 * HDIM * HDIM, whhb,
                b_ih, b_hh, nullptr, hbn);
        else
            gru_mfma<1><<<dim3((M_PAD / 128) * 4), dim3(256), 0, stream>>>(
                aggb, hbc, weffb + (size_t)l * 3 * HDIM * HDIM, whhb,
                b_ih, b_hh, hfF, hbn);
        unsigned short* tb = hbc; hbc = hbn; hbn = tb;
    }

    // ---- attention pooling + classifier (fp32 on final h) ----
    att_scores2<<<dim3((N_NODES + 31) / 32), dim3(256), 0, stream>>>(
        hfF, att_w1, att_b1, att_w2, att_b2, scores);
    seg_stats<<<dim3((N_GRAPHS * 64 + 255) / 256), dim3(256), 0, stream>>>(
        scores, starts, gmax, gden);
    node_weights<<<dim3((N_NODES + 255) / 256), dim3(256), 0, stream>>>(
        scores, batch, gmax, gden, wnode);
    pool_partial<<<dim3(N_GRAPHS, 4), dim3(256), 0, stream>>>(hfF, wnode, starts, ppart);
    pool_reduce<<<dim3(N_GRAPHS), dim3(256), 0, stream>>>(ppart, pooled);
    classify<<<dim3(N_GRAPHS), dim3(128), 0, stream>>>(pooled, cls_w1, cls_b1,
                                                       cls_w2, cls_b2, out);
}

// Round 19
// 489.270 us; speedup vs baseline: 1.0610x; 1.0610x over previous
//
#include <hip/hip_runtime.h>
#include <hip/hip_bf16.h>
#include <math.h>

#define N_NODES 20000
#define M_PAD   20096          // 157*128; all row-dim ws buffers padded to this
#define N_EDGES 320000
#define N_GRAPHS 64
#define D_IN 771
#define KP   800               // padded K for projection (multiple of 32)
#define HDIM 256
#define L_LAYERS 5

typedef __attribute__((ext_vector_type(8))) short  bf16x8;
typedef __attribute__((ext_vector_type(8))) unsigned short u16x8;
typedef __attribute__((ext_vector_type(4))) float  f32x4;

typedef __attribute__((address_space(3))) void       lds_void;
typedef __attribute__((address_space(1))) const void gconst_void;

__device__ __forceinline__ void gload16(const void* g, void* l) {
    __builtin_amdgcn_global_load_lds((gconst_void*)g, (lds_void*)l, 16, 0, 0);
}

__device__ __forceinline__ unsigned short f2bf(float f) {
    unsigned int u = __float_as_uint(f);
    return (unsigned short)((u + 0x7FFFu + ((u >> 16) & 1u)) >> 16);  // RNE
}
__device__ __forceinline__ float bf2f(unsigned short h) {
    return __uint_as_float(((unsigned int)h) << 16);
}

// swizzle: 16B slot XOR x(r), x(r)=(r>>1)&3  ->  2-way (free) bank aliasing
__device__ __forceinline__ int swz_src_elems(int lane, int lr) {
    return ((((lane & 3) * 16) ^ (((lr >> 1) & 3) << 4)) >> 1);
}
__device__ __forceinline__ int swz_read_bytes(int lane, int r) {
    return (((lane >> 4) * 16) ^ (((r >> 1) & 3) << 4));
}

// ---------------- prep kernels (bf16 casts / transposes, one-time) ----------
// 8 elems/thread (16B store, 32B of reads) — G13 vectorization.
__global__ __launch_bounds__(256)
void prep_x(const float* __restrict__ x, unsigned short* __restrict__ xb) {
    int chunk = blockIdx.x * 256 + threadIdx.x;     // 8-elem chunks
    if (chunk >= N_NODES * (KP / 8)) return;
    int r  = chunk / (KP / 8);
    int k0 = (chunk % (KP / 8)) * 8;
    const float* xr = x + (size_t)r * D_IN;
    u16x8 o;
    #pragma unroll
    for (int i = 0; i < 8; i++) {
        int k = k0 + i;
        o[i] = f2bf(k < D_IN ? xr[k] : 0.f);
    }
    *(u16x8*)(xb + (size_t)r * KP + k0) = o;
}
__global__ void prep_projw(const float* __restrict__ w, unsigned short* __restrict__ wt) {
    int i = blockIdx.x * 256 + threadIdx.x;                // over 256*800, wt[n][k]
    if (i >= HDIM * KP) return;
    int n = i / KP, k = i % KP;
    wt[i] = f2bf(k < D_IN ? w[(size_t)k * HDIM + n] : 0.f);
}
__global__ void prep_cast1(const float* __restrict__ a, unsigned short* __restrict__ ab,
                           int n) {
    int i = blockIdx.x * 256 + threadIdx.x;
    if (i < n) ab[i] = f2bf(a[i]);
}

// W_eff[l][c][j] = sum_t conv_w[l][j][t] * w_ih[c][t]   (fused msg+gi weight)
// fp32 tiled GEMM, bf16 output in [n=c][k=j] layout for gru staging.
__global__ __launch_bounds__(256)
void weff_gemm(const float* __restrict__ wih, const float* __restrict__ convw,
               unsigned short* __restrict__ weff) {
    __shared__ float As[16][68];
    __shared__ float Bs[16][68];
    const int tid = threadIdx.x;
    const int c0 = blockIdx.x * 64, j0 = blockIdx.y * 64;
    const int l  = blockIdx.z;
    const float* Wc = convw + (size_t)l * HDIM * HDIM;
    const int tm = (tid & 15) * 4, tn = (tid >> 4) * 4;
    const int ar = tid >> 2, ac = (tid & 3) * 4;
    float acc[4][4] = {};
    for (int t0 = 0; t0 < HDIM; t0 += 16) {
        float4 av = *(const float4*)(wih + (size_t)(c0 + ar) * HDIM + t0 + ac);
        float4 bv = *(const float4*)(Wc  + (size_t)(j0 + ar) * HDIM + t0 + ac);
        As[ac + 0][ar] = av.x; As[ac + 1][ar] = av.y;
        As[ac + 2][ar] = av.z; As[ac + 3][ar] = av.w;
        Bs[ac + 0][ar] = bv.x; Bs[ac + 1][ar] = bv.y;
        Bs[ac + 2][ar] = bv.z; Bs[ac + 3][ar] = bv.w;
        __syncthreads();
        #pragma unroll
        for (int kk = 0; kk < 16; kk++) {
            float aa[4] = {As[kk][tm], As[kk][tm+1], As[kk][tm+2], As[kk][tm+3]};
            float bb[4] = {Bs[kk][tn], Bs[kk][tn+1], Bs[kk][tn+2], Bs[kk][tn+3]};
            #pragma unroll
            for (int i = 0; i < 4; i++)
                #pragma unroll
                for (int j = 0; j < 4; j++) acc[i][j] += aa[i] * bb[j];
        }
        __syncthreads();
    }
    #pragma unroll
    for (int i = 0; i < 4; i++)
        #pragma unroll
        for (int j = 0; j < 4; j++)
            weff[(size_t)l * 3 * HDIM * HDIM + (size_t)(c0 + tm + i) * HDIM + j0 + tn + j] =
                f2bf(acc[i][j]);
}

// ---------------- generic bf16 MFMA GEMM: C[M,256] = A[M,K] @ Bt[N,K]^T -----
// 128x128 tile, 4 waves (2x2), wave tile 64x64. 2-phase double-buffered LDS.
// (used only for the input projection; bf16-only output)
template<int EPI>   // 0: plain, store Cb; 1: bias+relu, store Cb
__global__ __launch_bounds__(256)
void mm128(const unsigned short* __restrict__ A, int lda,
           const unsigned short* __restrict__ Bt, int ldb,
           const float* __restrict__ bias,
           unsigned short* __restrict__ Cb, int nk) {
    __shared__ char lds[32768];                 // 2 x (8KB A + 8KB B)
    const int tid = threadIdx.x;
    const int lane = tid & 63, wave = tid >> 6;
    const int wm = wave >> 1, wn = wave & 1;
    const int row0 = blockIdx.x * 128, col0 = blockIdx.y * 128;
    const int lr = lane >> 2;
    const int kle = swz_src_elems(lane, lr);

    const unsigned short* sA[2];
    const unsigned short* sB[2];
    #pragma unroll
    for (int j = 0; j < 2; ++j) {
        int c = wave * 2 + j;
        sA[j] = A  + (size_t)(row0 + c * 16 + lr) * lda + kle;
        sB[j] = Bt + (size_t)(col0 + c * 16 + lr) * ldb + kle;
    }

    f32x4 acc[4][4];
    #pragma unroll
    for (int i = 0; i < 4; i++)
        #pragma unroll
        for (int j = 0; j < 4; j++) acc[i][j] = (f32x4){0.f, 0.f, 0.f, 0.f};

    auto stage = [&](int buf, int ks) {
        #pragma unroll
        for (int j = 0; j < 2; ++j) {
            int c = wave * 2 + j;
            gload16(sA[j] + ks * 32, lds + buf * 16384 + c * 1024);
            gload16(sB[j] + ks * 32, lds + buf * 16384 + 8192 + c * 1024);
        }
    };

    stage(0, 0);
    __syncthreads();
    for (int ks = 0; ks < nk; ++ks) {
        const int cur = ks & 1;
        if (ks + 1 < nk) stage(cur ^ 1, ks + 1);
        char* L = lds + cur * 16384;
        bf16x8 af[4], bfr[4];
        #pragma unroll
        for (int f = 0; f < 4; ++f) {
            int r = wm * 64 + f * 16 + (lane & 15);
            af[f] = *(const bf16x8*)(L + r * 64 + swz_read_bytes(lane, r));
            int cb = wn * 64 + f * 16 + (lane & 15);
            bfr[f] = *(const bf16x8*)(L + 8192 + cb * 64 + swz_read_bytes(lane, cb));
        }
        #pragma unroll
        for (int i = 0; i < 4; i++)
            #pragma unroll
            for (int j = 0; j < 4; j++)
                acc[i][j] = __builtin_amdgcn_mfma_f32_16x16x32_bf16(af[i], bfr[j], acc[i][j], 0, 0, 0);
        if (ks + 1 < nk) __syncthreads();
    }
    #pragma unroll
    for (int i = 0; i < 4; i++) {
        #pragma unroll
        for (int j = 0; j < 4; j++) {
            int cc = col0 + wn * 64 + j * 16 + (lane & 15);
            #pragma unroll
            for (int ri = 0; ri < 4; ++ri) {
                int rr = row0 + wm * 64 + i * 16 + (lane >> 4) * 4 + ri;
                float v = acc[i][j][ri];
                if (EPI == 1) { v += bias[cc]; v = fmaxf(v, 0.f); }
                Cb[(size_t)rr * HDIM + cc] = f2bf(v);
            }
        }
    }
}

// ---------------- fused GRU v7 (R17, best measured): T3+T4 pipeline ---------
// 3x16KB LDS ring, prefetch depth 2. Per K-step: stage(k+2) -> ds_read/mfma(k)
// -> s_waitcnt vmcnt(4) (certify k+1's 4 loads; k+2's stay IN FLIGHT across
// the raw s_barrier). 42.7 -> 39.4us vs __syncthreads (whose implicit
// vmcnt(0) drained the same-iter prefetch — the long plateau's cause).
// R18's 2-row-tile variant regressed (occupancy 22.7->14.5%): inter-block TLP
// at 3 blocks/CU beats per-barrier compute amplification at 2 blocks/CU.
template<int FINAL>
__global__ __launch_bounds__(256, 3)
void gru_mfma(const unsigned short* __restrict__ aggb, const unsigned short* __restrict__ hb,
              const unsigned short* __restrict__ weff, const unsigned short* __restrict__ whh,
              const float* __restrict__ bih, const float* __restrict__ bhh,
              float* __restrict__ hfN, unsigned short* __restrict__ hbN) {
    __shared__ char lds[49152];                   // 3 x 16KB ring
    const int tid = threadIdx.x;
    const int lane = tid & 63, wave = tid >> 6;   // 4 waves
    const int wm = wave >> 1, wn = wave & 1;      // 2 x 2
    const int bx = blockIdx.x;                    // [0, 1256)
    const int col0 = (bx & 3) * 64;
    const int rowt = ((bx >> 2) & 1) * 157 + (bx >> 3);
    const int row0 = rowt * 64;
    const int lr = lane >> 2;
    const int laneoff = lr * HDIM + swz_src_elems(lane, lr);  // per-lane elems

    // hoisted per-wave staging sources, phase 0 (agg/weff) and 1 (h/whh).
    const unsigned short* p0[4];
    const unsigned short* p1[4];
    #pragma unroll
    for (int j = 0; j < 4; ++j) {
        const unsigned short *q0, *q1;
        int uo;
        if (wave == 0) { q0 = aggb; q1 = hb; uo = (row0 + j * 16) * HDIM; }
        else {
            int s = wave - 1;
            q0 = weff; q1 = whh;
            uo = (s * HDIM + col0 + j * 16) * HDIM;
        }
        uo = __builtin_amdgcn_readfirstlane(uo);
        p0[j] = q0 + uo + laneoff;
        p1[j] = q1 + uo + laneoff;
    }

    f32x4 accR[2][2], accZ[2][2], accNI[2][2], accNH[2][2];
    #pragma unroll
    for (int i = 0; i < 2; i++)
        #pragma unroll
        for (int j = 0; j < 2; j++) {
            accR[i][j] = (f32x4){0.f, 0.f, 0.f, 0.f};
            accZ[i][j] = (f32x4){0.f, 0.f, 0.f, 0.f};
            accNI[i][j] = (f32x4){0.f, 0.f, 0.f, 0.f};
            accNH[i][j] = (f32x4){0.f, 0.f, 0.f, 0.f};
        }

    auto stage = [&](int buf, int gks) {
        #pragma unroll
        for (int j = 0; j < 4; ++j) {
            const unsigned short* s = (gks < 8 ? p0[j] : p1[j]) + (gks & 7) * 32;
            gload16(s, lds + buf * 16384 + (wave * 4 + j) * 1024);
        }
    };

    // prologue: 2-deep prefetch; certify buf0, keep buf1 in flight.
    stage(0, 0);
    stage(1, 1);
    asm volatile("s_waitcnt vmcnt(4)" ::: "memory");
    __builtin_amdgcn_s_barrier();

    #pragma unroll
    for (int ks = 0; ks < 16; ++ks) {
        if (ks + 2 < 16) stage((ks + 2) % 3, ks + 2);
        char* L = lds + (ks % 3) * 16384;
        bf16x8 a[2], br[2], bz[2], bn[2];
        #pragma unroll
        for (int f = 0; f < 2; ++f) {
            int r = wm * 32 + f * 16 + (lane & 15);
            a[f] = *(const bf16x8*)(L + r * 64 + swz_read_bytes(lane, r));
            int rb = wn * 32 + f * 16 + (lane & 15);
            int so = rb * 64 + swz_read_bytes(lane, rb);
            br[f] = *(const bf16x8*)(L + 4096 + so);
            bz[f] = *(const bf16x8*)(L + 8192 + so);
            bn[f] = *(const bf16x8*)(L + 12288 + so);
        }
        #pragma unroll
        for (int fr = 0; fr < 2; fr++)
            #pragma unroll
            for (int fc = 0; fc < 2; fc++) {
                accR[fr][fc] = __builtin_amdgcn_mfma_f32_16x16x32_bf16(a[fr], br[fc], accR[fr][fc], 0, 0, 0);
                accZ[fr][fc] = __builtin_amdgcn_mfma_f32_16x16x32_bf16(a[fr], bz[fc], accZ[fr][fc], 0, 0, 0);
                if (ks < 8)
                    accNI[fr][fc] = __builtin_amdgcn_mfma_f32_16x16x32_bf16(a[fr], bn[fc], accNI[fr][fc], 0, 0, 0);
                else
                    accNH[fr][fc] = __builtin_amdgcn_mfma_f32_16x16x32_bf16(a[fr], bn[fc], accNH[fr][fc], 0, 0, 0);
            }
        if (ks < 14) {
            asm volatile("s_waitcnt vmcnt(4)" ::: "memory");   // k+1 done, k+2 in flight
            __builtin_amdgcn_s_barrier();
        } else if (ks == 14) {
            asm volatile("s_waitcnt vmcnt(0)" ::: "memory");   // drain last tile
            __builtin_amdgcn_s_barrier();
        }
    }
    #pragma unroll
    for (int fr = 0; fr < 2; fr++)
        #pragma unroll
        for (int fc = 0; fc < 2; fc++) {
            int cc = col0 + wn * 32 + fc * 16 + (lane & 15);
            float brz = bih[cc]            + bhh[cc];
            float bzz = bih[HDIM + cc]     + bhh[HDIM + cc];
            float bin = bih[2 * HDIM + cc];
            float bhn = bhh[2 * HDIM + cc];
            #pragma unroll
            for (int ri = 0; ri < 4; ++ri) {
                int rr = row0 + wm * 32 + fr * 16 + (lane >> 4) * 4 + ri;
                float xr = accR[fr][fc][ri] + brz;
                float xz = accZ[fr][fc][ri] + bzz;
                float gn = accNI[fr][fc][ri] + bin;
                float hn = accNH[fr][fc][ri] + bhn;
                float r_ = 1.f / (1.f + expf(-xr));
                float z_ = 1.f / (1.f + expf(-xz));
                float n_ = tanhf(gn + r_ * hn);
                float ho = bf2f(hb[(size_t)rr * HDIM + cc]);  // L2-hot
                float v  = (1.f - z_) * n_ + z_ * ho;
                if (FINAL) hfN[(size_t)rr * HDIM + cc] = v;
                hbN[(size_t)rr * HDIM + cc] = f2bf(v);
            }
        }
}

// -------------------------- CSR build ---------------------------------------
__global__ void edge_count(const int* __restrict__ ei, int* __restrict__ deg, int E) {
    int e = blockIdx.x * 256 + threadIdx.x;
    if (e < E) atomicAdd(&deg[ei[E + e]], 1);
}
__global__ __launch_bounds__(1024)
void scan_rowptr(const int* __restrict__ deg, int* __restrict__ rowptr, int N) {
    __shared__ int bs[1024];
    const int tid = threadIdx.x;
    const int CH = (N + 1023) / 1024;
    const int base = tid * CH;
    int sum = 0;
    for (int i = 0; i < CH; i++) { int idx = base + i; sum += (idx < N) ? deg[idx] : 0; }
    bs[tid] = sum; __syncthreads();
    for (int off = 1; off < 1024; off <<= 1) {
        int v = (tid >= off) ? bs[tid - off] : 0;
        __syncthreads();
        bs[tid] += v;
        __syncthreads();
    }
    int run = (tid > 0) ? bs[tid - 1] : 0;
    for (int i = 0; i < CH; i++) {
        int idx = base + i;
        if (idx < N) { rowptr[idx] = run; run += deg[idx]; }
    }
    if (tid == 0) rowptr[N] = bs[1023];
}
__global__ void edge_bucket(const int* __restrict__ ei, int* __restrict__ cursor,
                            int* __restrict__ csrc, int E) {
    int e = blockIdx.x * 256 + threadIdx.x;
    if (e < E) {
        int d = ei[E + e];
        int p = atomicAdd(&cursor[d], 1);
        csrc[p] = ei[e];
    }
}

// agg v3: one wave per node; QUARTER-wave (16 lanes) per edge, 32B/lane,
// 2x unroll -> 8 row-gathers in flight; combine via shfl_xor(16,32).
__global__ __launch_bounds__(256)
void agg_bf16(const unsigned short* __restrict__ m, const int* __restrict__ rowptr,
              const int* __restrict__ csrc, unsigned short* __restrict__ agg, int N) {
    int wv = (blockIdx.x * 256 + threadIdx.x) >> 6;
    int lane = threadIdx.x & 63;
    if (wv >= N) return;
    const int q = lane >> 4, l16 = lane & 15;
    int s0 = rowptr[wv], s1 = rowptr[wv + 1];
    float a[16] = {};
    int e = s0 + q;
    for (; e + 4 < s1; e += 8) {            // 2 edges per quarter in flight
        const unsigned short* rA = m + (size_t)csrc[e] * HDIM + l16 * 16;
        const unsigned short* rB = m + (size_t)csrc[e + 4] * HDIM + l16 * 16;
        u16x8 vA0 = *(const u16x8*)rA, vA1 = *(const u16x8*)(rA + 8);
        u16x8 vB0 = *(const u16x8*)rB, vB1 = *(const u16x8*)(rB + 8);
        #pragma unroll
        for (int i = 0; i < 8; i++) {
            a[i]     += bf2f(vA0[i]) + bf2f(vB0[i]);
            a[8 + i] += bf2f(vA1[i]) + bf2f(vB1[i]);
        }
    }
    for (; e < s1; e += 4) {
        const unsigned short* rA = m + (size_t)csrc[e] * HDIM + l16 * 16;
        u16x8 vA0 = *(const u16x8*)rA, vA1 = *(const u16x8*)(rA + 8);
        #pragma unroll
        for (int i = 0; i < 8; i++) {
            a[i]     += bf2f(vA0[i]);
            a[8 + i] += bf2f(vA1[i]);
        }
    }
    #pragma unroll
    for (int i = 0; i < 16; i++) {
        a[i] += __shfl_xor(a[i], 16);
        a[i] += __shfl_xor(a[i], 32);
    }
    if (q == 0) {
        u16x8 o0, o1;
        #pragma unroll
        for (int i = 0; i < 8; i++) { o0[i] = f2bf(a[i]); o1[i] = f2bf(a[8 + i]); }
        *(u16x8*)(agg + (size_t)wv * HDIM + l16 * 16)     = o0;
        *(u16x8*)(agg + (size_t)wv * HDIM + l16 * 16 + 8) = o1;
    }
}

// -------------------------- attention + head --------------------------------
__global__ void seg_starts(const int* __restrict__ batch, int* __restrict__ starts,
                           int N, int G) {
    int n = blockIdx.x * 256 + threadIdx.x;
    if (n > N) return;
    int b  = (n < N) ? batch[n] : G;
    int bp = (n == 0) ? -1 : batch[n - 1];
    for (int g = bp + 1; g <= b; g++) starts[g] = n;
}

// att scores v2: 32-row tiles (625 blocks, 2x waves/SIMD), float4 LDS reads.
__global__ __launch_bounds__(256)
void att_scores2(const float* __restrict__ h, const float* __restrict__ w1,
                 const float* __restrict__ b1, const float* __restrict__ w2,
                 const float* __restrict__ b2, float* __restrict__ scores) {
    __shared__ float As[16][36];
    __shared__ float Bs[16][132];
    __shared__ float red[32][33];
    const int tid = threadIdx.x;
    const int row0 = blockIdx.x * 32;
    const int tm = (tid & 7) * 4, tn = (tid >> 3) * 4;
    const int ar = tid >> 3, ac = (tid & 7) * 2;    // A stage: 32 rows x 16k, 2/thread
    const int br = tid >> 4, bc = (tid & 15) * 8;   // B stage: 16k x 128, 8/thread
    float acc[4][4] = {};
    for (int k0 = 0; k0 < HDIM; k0 += 16) {
        float2 av = {0.f, 0.f};
        int arow = row0 + ar;
        if (arow < N_NODES) av = *(const float2*)(h + (size_t)arow * HDIM + k0 + ac);
        As[ac][ar] = av.x; As[ac + 1][ar] = av.y;
        *(float4*)&Bs[br][bc]     = *(const float4*)(w1 + (size_t)(k0 + br) * 128 + bc);
        *(float4*)&Bs[br][bc + 4] = *(const float4*)(w1 + (size_t)(k0 + br) * 128 + bc + 4);
        __syncthreads();
        #pragma unroll
        for (int kk = 0; kk < 16; kk++) {
            float4 a4 = *(const float4*)&As[kk][tm];
            float4 b4 = *(const float4*)&Bs[kk][tn];
            float aa[4] = {a4.x, a4.y, a4.z, a4.w};
            float bb[4] = {b4.x, b4.y, b4.z, b4.w};
            #pragma unroll
            for (int i = 0; i < 4; i++)
                #pragma unroll
                for (int j = 0; j < 4; j++) acc[i][j] += aa[i] * bb[j];
        }
        __syncthreads();
    }
    #pragma unroll
    for (int i = 0; i < 4; i++) {
        float s = 0.f;
        #pragma unroll
        for (int j = 0; j < 4; j++)
            s += tanhf(acc[i][j] + b1[tn + j]) * w2[tn + j];
        red[tm + i][tid >> 3] = s;
    }
    __syncthreads();
    if (tid < 32) {
        float s = 0.f;
        #pragma unroll
        for (int g = 0; g < 32; g++) s += red[tid][g];
        int n = row0 + tid;
        if (n < N_NODES) scores[n] = s + b2[0];
    }
}

// per-graph max + denom: one wave per graph
__global__ __launch_bounds__(256)
void seg_stats(const float* __restrict__ scores, const int* __restrict__ starts,
               float* __restrict__ gmax, float* __restrict__ gden) {
    int wv = (blockIdx.x * 256 + threadIdx.x) >> 6;
    int lane = threadIdx.x & 63;
    if (wv >= N_GRAPHS) return;
    int s0 = starts[wv], s1 = starts[wv + 1];
    float mx = -1e30f;
    for (int n = s0 + lane; n < s1; n += 64) mx = fmaxf(mx, scores[n]);
    #pragma unroll
    for (int off = 32; off > 0; off >>= 1) mx = fmaxf(mx, __shfl_xor(mx, off));
    float se = 0.f;
    for (int n = s0 + lane; n < s1; n += 64) se += expf(scores[n] - mx);
    #pragma unroll
    for (int off = 32; off > 0; off >>= 1) se += __shfl_xor(se, off);
    if (lane == 0) { gmax[wv] = mx; gden[wv] = se; }
}

__global__ void node_weights(const float* __restrict__ scores, const int* __restrict__ batch,
                             const float* __restrict__ gmax, const float* __restrict__ gden,
                             float* __restrict__ wn) {
    int n = blockIdx.x * 256 + threadIdx.x;
    if (n >= N_NODES) return;
    int g = batch[n];
    float d = gden[g];
    wn[n] = (d > 0.f) ? expf(scores[n] - gmax[g]) / d : 0.f;
}

// deterministic 4-stripe weighted pool: block (g,s) handles nodes n≡s (mod 4)
__global__ __launch_bounds__(256)
void pool_partial(const float* __restrict__ h, const float* __restrict__ wn,
                  const int* __restrict__ starts, float* __restrict__ part) {
    int g = blockIdx.x, s = blockIdx.y, tid = threadIdx.x;
    int s0 = starts[g], s1 = starts[g + 1];
    float acc = 0.f;
    for (int n = s0 + s; n < s1; n += 4)
        acc += wn[n] * h[(size_t)n * HDIM + tid];
    part[((size_t)(g * 4 + s)) * HDIM + tid] = acc;
}
__global__ __launch_bounds__(256)
void pool_reduce(const float* __restrict__ part, float* __restrict__ pooled) {
    int g = blockIdx.x, tid = threadIdx.x;
    float s = 0.f;
    #pragma unroll
    for (int i = 0; i < 4; i++) s += part[((size_t)(g * 4 + i)) * HDIM + tid];
    pooled[g * HDIM + tid] = s;
}

__global__ __launch_bounds__(128)
void classify(const float* __restrict__ pooled, const float* __restrict__ w1,
              const float* __restrict__ b1, const float* __restrict__ w2,
              const float* __restrict__ b2, float* __restrict__ out) {
    int g = blockIdx.x;
    int tid = threadIdx.x;
    float acc = 0.f;
    for (int k = 0; k < HDIM; k++) acc += pooled[g * HDIM + k] * w1[k * 128 + tid];
    float t = fmaxf(acc + b1[tid], 0.f);
    float v = t * w2[tid];
    __shared__ float red[128];
    red[tid] = v; __syncthreads();
    for (int off = 64; off > 0; off >>= 1) {
        if (tid < off) red[tid] += red[tid + off];
        __syncthreads();
    }
    if (tid == 0) out[g] = red[0] + b2[0];
}

// ---------------------------------------------------------------------------
extern "C" void kernel_launch(void* const* d_in, const int* in_sizes, int n_in,
                              void* d_out, int out_size, void* d_ws, size_t ws_size,
                              hipStream_t stream) {
    const float* x      = (const float*)d_in[0];
    const int*   ei     = (const int*)  d_in[1];
    const int*   batch  = (const int*)  d_in[2];
    const float* proj_w = (const float*)d_in[3];
    const float* proj_b = (const float*)d_in[4];
    const float* conv_w = (const float*)d_in[5];
    const float* w_ih   = (const float*)d_in[6];
    const float* w_hh   = (const float*)d_in[7];
    const float* b_ih   = (const float*)d_in[8];
    const float* b_hh   = (const float*)d_in[9];
    const float* att_w1 = (const float*)d_in[10];
    const float* att_b1 = (const float*)d_in[11];
    const float* att_w2 = (const float*)d_in[12];
    const float* att_b2 = (const float*)d_in[13];
    const float* cls_w1 = (const float*)d_in[14];
    const float* cls_b1 = (const float*)d_in[15];
    const float* cls_w2 = (const float*)d_in[16];
    const float* cls_b2 = (const float*)d_in[17];
    float* out = (float*)d_out;

    char* ws = (char*)d_ws;
    size_t off = 0;
    auto alloc = [&](size_t bytes) -> void* {
        void* p = ws + off;
        off = (off + bytes + 255) & ~(size_t)255;
        return p;
    };
    // persistent
    float*          hfF    = (float*)         alloc((size_t)M_PAD * HDIM * 4);  // final h (attention)
    unsigned short* hb0    = (unsigned short*)alloc((size_t)M_PAD * HDIM * 2);
    unsigned short* hb1    = (unsigned short*)alloc((size_t)M_PAD * HDIM * 2);
    unsigned short* whhb   = (unsigned short*)alloc((size_t)3 * HDIM * HDIM * 2);
    unsigned short* weffb  = (unsigned short*)alloc((size_t)L_LAYERS * 3 * HDIM * HDIM * 2);
    unsigned short* projWT = (unsigned short*)alloc((size_t)HDIM * KP * 2);
    int*   rowptr = (int*)  alloc((N_NODES + 1) * 4);
    int*   cursor = (int*)  alloc((N_NODES + 1) * 4);
    int*   deg    = (int*)  alloc(N_NODES * 4);
    int*   csrc   = (int*)  alloc(N_EDGES * 4);
    float* scores = (float*)alloc(N_NODES * 4);
    int*   starts = (int*)  alloc((N_GRAPHS + 1) * 4);
    float* gmax   = (float*)alloc(N_GRAPHS * 4);
    float* gden   = (float*)alloc(N_GRAPHS * 4);
    float* wnode  = (float*)alloc(N_NODES * 4);
    float* ppart  = (float*)alloc((size_t)N_GRAPHS * 4 * HDIM * 4);
    float* pooled = (float*)alloc((size_t)N_GRAPHS * HDIM * 4);
    // union region: xb (proj phase) overlaps aggb (layer phase)
    char* U = (char*)alloc((size_t)M_PAD * KP * 2);
    unsigned short* xb   = (unsigned short*)U;
    unsigned short* aggb = (unsigned short*)U;
    (void)ws_size; (void)in_sizes; (void)n_in; (void)out_size;

    // ---- one-time prep ----
    prep_x     <<<dim3((N_NODES * (KP / 8) + 255) / 256), dim3(256), 0, stream>>>(x, xb);
    prep_projw <<<dim3((HDIM * KP) / 256), dim3(256), 0, stream>>>(proj_w, projWT);
    prep_cast1 <<<dim3((3 * HDIM * HDIM) / 256), dim3(256), 0, stream>>>(
        w_hh, whhb, 3 * HDIM * HDIM);
    // fused msg+gi weights: W_eff[l] = Wih . Wc[l]^T contraction
    weff_gemm<<<dim3(12, 4, L_LAYERS), dim3(256), 0, stream>>>(w_ih, conv_w, weffb);

    // ---- input projection (+bias+relu) -> hb0 (bf16 only) ----
    mm128<1><<<dim3(M_PAD / 128, 2), dim3(256), 0, stream>>>(
        xb, KP, projWT, KP, proj_b, hb0, KP / 32);

    // ---- CSR by dst ----
    hipMemsetAsync(deg, 0, N_NODES * 4, stream);
    edge_count<<<dim3((N_EDGES + 255) / 256), dim3(256), 0, stream>>>(ei, deg, N_EDGES);
    scan_rowptr<<<dim3(1), dim3(1024), 0, stream>>>(deg, rowptr, N_NODES);
    hipMemcpyAsync(cursor, rowptr, (N_NODES + 1) * 4, hipMemcpyDeviceToDevice, stream);
    edge_bucket<<<dim3((N_EDGES + 255) / 256), dim3(256), 0, stream>>>(ei, cursor, csrc, N_EDGES);
    seg_starts<<<dim3((N_NODES + 256) / 256), dim3(256), 0, stream>>>(batch, starts,
                                                                      N_NODES, N_GRAPHS);

    // ---- 5 message-passing layers (msg GEMM folded into W_eff; bf16 h) ----
    unsigned short* hbc = hb0;  unsigned short* hbn = hb1;
    for (int l = 0; l < L_LAYERS; l++) {
        agg_bf16<<<dim3((N_NODES * 64) / 256), dim3(256), 0, stream>>>(
            hbc, rowptr, csrc, aggb, N_NODES);
        if (l < L_LAYERS - 1)
            gru_mfma<0><<<dim3((M_PAD / 64) * 4), dim3(256), 0, stream>>>(
                aggb, hbc, weffb + (size_t)l * 3 * HDIM * HDIM, whhb,
                b_ih, b_hh, nullptr, hbn);
        else
            gru_mfma<1><<<dim3((M_PAD / 64) * 4), dim3(256), 0, stream>>>(
                aggb, hbc, weffb + (size_t)l * 3 * HDIM * HDIM, whhb,
                b_ih, b_hh, hfF, hbn);
        unsigned short* tb = hbc; hbc = hbn; hbn = tb;
    }

    // ---- attention pooling + classifier (fp32 on final h) ----
    att_scores2<<<dim3((N_NODES + 31) / 32), dim3(256), 0, stream>>>(
        hfF, att_w1, att_b1, att_w2, att_b2, scores);
    seg_stats<<<dim3((N_GRAPHS * 64 + 255) / 256), dim3(256), 0, stream>>>(
        scores, starts, gmax, gden);
    node_weights<<<dim3((N_NODES + 255) / 256), dim3(256), 0, stream>>>(
        scores, batch, gmax, gden, wnode);
    pool_partial<<<dim3(N_GRAPHS, 4), dim3(256), 0, stream>>>(hfF, wnode, starts, ppart);
    pool_reduce<<<dim3(N_GRAPHS), dim3(256), 0, stream>>>(ppart, pooled);
    classify<<<dim3(N_GRAPHS), dim3(128), 0, stream>>>(pooled, cls_w1, cls_b1,
                                                       cls_w2, cls_b2, out);
}